// Round 11
// baseline (245.298 us; speedup 1.0000x reference)
//
#include <hip/hip_runtime.h>

// MHA: B=2, S=2048, D=1024, H=16, hd=64. fp32 in/out, bf16 MFMA internally.
// R10: (a) maskT prep (transposed + log2e-scaled) -> attn mask loads become
// coalesced scalars (16/iter, 4 sectors each vs 64); in-loop drain vmcnt(18).
// (b) GEMMs: register-prefetch pipeline (global->VGPR dist-2, ds_write dist-1,
// vmcnt(0) covers a full iteration of latency). Attn structure else = R9.

typedef __bf16 bf16;
typedef __bf16 bf16x2 __attribute__((ext_vector_type(2)));
typedef __bf16 bf16x4 __attribute__((ext_vector_type(4)));
typedef __bf16 bf16x8 __attribute__((ext_vector_type(8)));
typedef float f32x4 __attribute__((ext_vector_type(4)));

#define MFMA(a, b, c) __builtin_amdgcn_mfma_f32_16x16x32_bf16((a), (b), (c), 0, 0, 0)

#if __has_builtin(__builtin_amdgcn_exp2f)
#define EXP2(x) __builtin_amdgcn_exp2f(x)
#else
#define EXP2(x) exp2f(x)
#endif

__device__ __forceinline__ void load_lds16(const bf16* g, void* l) {
    __builtin_amdgcn_global_load_lds(
        (const __attribute__((address_space(1))) unsigned int*)g,
        (__attribute__((address_space(3))) unsigned int*)l, 16, 0, 0);
}

// ---------------- cast fp32 -> bf16, 4 elems/thread ----------------
__global__ void cast4_kernel(const float* __restrict__ in, bf16* __restrict__ out, int n4) {
    int i = blockIdx.x * blockDim.x + threadIdx.x;
    if (i < n4) {
        float4 v = ((const float4*)in)[i];
        bf16x4 o = {(bf16)v.x, (bf16)v.y, (bf16)v.z, (bf16)v.w};
        ((bf16x4*)out)[i] = o;
    }
}

// ---------------- transpose + cast: in [R,C] fp32 -> out [C,R] bf16 ----------------
__global__ void transpose_cast_kernel(const float* __restrict__ in, bf16* __restrict__ out,
                                      int R, int C) {
    __shared__ float tile[32][33];
    int bx = blockIdx.x * 32;
    int by = blockIdx.y * 32;
    int tx = threadIdx.x, ty = threadIdx.y;  // (32,8)
    for (int i = 0; i < 32; i += 8)
        tile[ty + i][tx] = in[(size_t)(by + ty + i) * C + bx + tx];
    __syncthreads();
    for (int i = 0; i < 32; i += 8)
        out[(size_t)(bx + ty + i) * R + by + tx] = (bf16)tile[tx][ty + i];
}

// ---------------- transpose + scale fp32: maskT[s][q] = mask[q][s] * log2e ----------------
__global__ void transpose_scale_kernel(const float* __restrict__ in, float* __restrict__ out) {
    __shared__ float tile[32][33];
    const float L2E = 1.44269504089f;
    int bx = blockIdx.x * 32;  // s base
    int by = blockIdx.y * 32;  // q base
    int tx = threadIdx.x, ty = threadIdx.y;  // (32,8)
    for (int i = 0; i < 32; i += 8)
        tile[ty + i][tx] = in[(size_t)(by + ty + i) * 2048 + bx + tx];
    __syncthreads();
    for (int i = 0; i < 32; i += 8)
        out[(size_t)(bx + ty + i) * 2048 + by + tx] = tile[tx][ty + i] * L2E;
}

// ---------------- GEMM1: X[4096,1024] @ Wqkv -> scatter Q,K,VT (bf16) ----------------
// 128x128 tile, BK=32, 32 iters. Register-prefetch pipeline:
//   regs hold tile j+1 (loaded iter j-1); LDS[j&1] holds tile j.
//   iter j: lgkmcnt(0); s_barrier; vmcnt(0); ds_write tile j+1 -> LDS[(j+1)&1];
//           issue global loads tile j+2 -> regs; compute tile j.
// Source-side XOR swizzle preserved (slot cc of row holds chunk cc^(row&3)).
__global__ __launch_bounds__(256) void gemm_qkv_kernel(
    const bf16* __restrict__ A, const bf16* __restrict__ BT,
    const float* __restrict__ bias,
    bf16* __restrict__ Q, bf16* __restrict__ K, bf16* __restrict__ VT) {
    __shared__ __attribute__((aligned(16))) char lds[2][16384];  // A[0,8K) B[8K,16K)
    int bm = blockIdx.x, bn = blockIdx.y;
    int t = threadIdx.x;
    int w = t >> 6, lane = t & 63, g = lane >> 4, l16 = lane & 15;
    int wm = (w >> 1) * 64, wn = (w & 1) * 64;
    f32x4 acc[4][4] = {};
    const bf16* Ablk = A + (size_t)(bm * 128) * 1024;
    const bf16* Bblk = BT + (size_t)(bn * 128) * 1024;
    int srow = t >> 2;
    int scg = (t & 3) ^ (srow & 3);
    const bf16* ag0 = Ablk + (size_t)srow * 1024 + scg * 8;
    const bf16* ag1 = ag0 + 64 * 1024;
    const bf16* bg0 = Bblk + (size_t)srow * 1024 + scg * 8;
    const bf16* bg1 = bg0 + 64 * 1024;

    // prologue: tile0 -> regs -> LDS[0]; tile1 -> regs
    bf16x8 ra0 = *(const bf16x8*)(ag0);
    bf16x8 ra1 = *(const bf16x8*)(ag1);
    bf16x8 rb0 = *(const bf16x8*)(bg0);
    bf16x8 rb1 = *(const bf16x8*)(bg1);
    asm volatile("s_waitcnt vmcnt(0)" ::: "memory");
    *(bf16x8*)(lds[0] + t * 16) = ra0;
    *(bf16x8*)(lds[0] + 4096 + t * 16) = ra1;
    *(bf16x8*)(lds[0] + 8192 + t * 16) = rb0;
    *(bf16x8*)(lds[0] + 12288 + t * 16) = rb1;
    ra0 = *(const bf16x8*)(ag0 + 32);
    ra1 = *(const bf16x8*)(ag1 + 32);
    rb0 = *(const bf16x8*)(bg0 + 32);
    rb1 = *(const bf16x8*)(bg1 + 32);

    int sw = l16 & 3;
#pragma unroll 2
    for (int j = 0; j < 32; j++) {
        asm volatile("s_waitcnt lgkmcnt(0)" ::: "memory");
        asm volatile("s_barrier" ::: "memory");
        asm volatile("s_waitcnt vmcnt(0)" ::: "memory");
        char* dst = lds[(j + 1) & 1];
        *(bf16x8*)(dst + t * 16) = ra0;
        *(bf16x8*)(dst + 4096 + t * 16) = ra1;
        *(bf16x8*)(dst + 8192 + t * 16) = rb0;
        *(bf16x8*)(dst + 12288 + t * 16) = rb1;
        int jp = j + 2 < 32 ? j + 2 : 31;
        ra0 = *(const bf16x8*)(ag0 + jp * 32);
        ra1 = *(const bf16x8*)(ag1 + jp * 32);
        rb0 = *(const bf16x8*)(bg0 + jp * 32);
        rb1 = *(const bf16x8*)(bg1 + jp * 32);

        const bf16* As = (const bf16*)lds[j & 1];
        const bf16* Bs = (const bf16*)(lds[j & 1] + 8192);
        bf16x8 af[4], bfr[4];
#pragma unroll
        for (int mi = 0; mi < 4; mi++) {
            int row = wm + mi * 16 + l16;
            af[mi] = *(const bf16x8*)(&As[row * 32 + (g ^ sw) * 8]);
        }
#pragma unroll
        for (int ni = 0; ni < 4; ni++) {
            int row = wn + ni * 16 + l16;
            bfr[ni] = *(const bf16x8*)(&Bs[row * 32 + (g ^ sw) * 8]);
        }
#pragma unroll
        for (int mi = 0; mi < 4; mi++)
#pragma unroll
            for (int ni = 0; ni < 4; ni++)
                acc[mi][ni] = MFMA(bfr[ni], af[mi], acc[mi][ni]);  // D^T
    }
    __syncthreads();  // drain everything before LDS reuse as vtile

    bf16* vt = (bf16*)lds;  // V-half transpose tile [64 d][136 s]
    int b = bm >> 4;
    int row0 = (bm & 15) * 128 + wm;
    int half_col = bn * 128 + wn;
    int h = half_col / 192, tt = half_col % 192;  // wave-uniform
    size_t bh = (size_t)(b * 16 + h);

    if (tt < 128) {
        bf16* base = (tt == 0 ? Q : K) + bh * 2048 * 64;
#pragma unroll
        for (int mi = 0; mi < 4; mi++) {
#pragma unroll
            for (int ni = 0; ni < 4; ni++) {
                int d0 = ni * 16 + g * 4;
                float4 bv = *(const float4*)(&bias[half_col + d0]);
                int s = row0 + mi * 16 + l16;
                bf16x4 pk = {(bf16)(acc[mi][ni][0] + bv.x), (bf16)(acc[mi][ni][1] + bv.y),
                             (bf16)(acc[mi][ni][2] + bv.z), (bf16)(acc[mi][ni][3] + bv.w)};
                *(bf16x4*)(&base[(size_t)s * 64 + d0]) = pk;
            }
        }
    } else {
#pragma unroll
        for (int mi = 0; mi < 4; mi++) {
            int s_local = wm + mi * 16 + l16;
#pragma unroll
            for (int ni = 0; ni < 4; ni++) {
                int d0 = ni * 16 + g * 4;
                float4 bv = *(const float4*)(&bias[half_col + d0]);
                vt[(d0 + 0) * 136 + s_local] = (bf16)(acc[mi][ni][0] + bv.x);
                vt[(d0 + 1) * 136 + s_local] = (bf16)(acc[mi][ni][1] + bv.y);
                vt[(d0 + 2) * 136 + s_local] = (bf16)(acc[mi][ni][2] + bv.z);
                vt[(d0 + 3) * 136 + s_local] = (bf16)(acc[mi][ni][3] + bv.w);
            }
        }
    }
    __syncthreads();

    int hc0 = bn * 128, hc1 = bn * 128 + 64;
    int vhalf = (hc0 % 192 == 128) ? 0 : ((hc1 % 192 == 128) ? 1 : -1);
    if (vhalf >= 0) {
        int vcol = bn * 128 + vhalf * 64;
        size_t vbh = (size_t)(b * 16 + vcol / 192);
        int d = t >> 2, ch = t & 3;
        const bf16* src = &vt[d * 136 + ch * 32];
        bf16* dstp = &VT[(vbh * 64 + d) * 2048 + (bm & 15) * 128 + ch * 32];
#pragma unroll
        for (int k = 0; k < 4; k++)
            *(bf16x8*)(&dstp[k * 8]) = *(const bf16x8*)(&src[k * 8]);
    }
}

// ---------------- GEMM3: vals[4096,1024] @ Wout -> out fp32 ----------------
// 128x64 tile (grid 32x16), BK=32. Same register-prefetch pipeline, 3 streams.
__global__ __launch_bounds__(256) void gemm_out_kernel(
    const bf16* __restrict__ A, const bf16* __restrict__ BT,
    const float* __restrict__ bias, float* __restrict__ out) {
    __shared__ __attribute__((aligned(16))) char lds[2][12288];  // A[0,8K) B[8K,12K)
    int bm = blockIdx.x, bn = blockIdx.y;
    int t = threadIdx.x;
    int w = t >> 6, lane = t & 63, g = lane >> 4, l16 = lane & 15;
    int wm = (w >> 1) * 64, wn = (w & 1) * 32;
    f32x4 acc[4][2] = {};
    const bf16* Ablk = A + (size_t)(bm * 128) * 1024;
    const bf16* Bblk = BT + (size_t)(bn * 64) * 1024;
    int srow = t >> 2;
    int scg = (t & 3) ^ (srow & 3);
    const bf16* ag0 = Ablk + (size_t)srow * 1024 + scg * 8;
    const bf16* ag1 = ag0 + 64 * 1024;
    const bf16* bg0 = Bblk + (size_t)srow * 1024 + scg * 8;

    bf16x8 ra0 = *(const bf16x8*)(ag0);
    bf16x8 ra1 = *(const bf16x8*)(ag1);
    bf16x8 rb0 = *(const bf16x8*)(bg0);
    asm volatile("s_waitcnt vmcnt(0)" ::: "memory");
    *(bf16x8*)(lds[0] + t * 16) = ra0;
    *(bf16x8*)(lds[0] + 4096 + t * 16) = ra1;
    *(bf16x8*)(lds[0] + 8192 + t * 16) = rb0;
    ra0 = *(const bf16x8*)(ag0 + 32);
    ra1 = *(const bf16x8*)(ag1 + 32);
    rb0 = *(const bf16x8*)(bg0 + 32);

    int sw = l16 & 3;
#pragma unroll 2
    for (int j = 0; j < 32; j++) {
        asm volatile("s_waitcnt lgkmcnt(0)" ::: "memory");
        asm volatile("s_barrier" ::: "memory");
        asm volatile("s_waitcnt vmcnt(0)" ::: "memory");
        char* dst = lds[(j + 1) & 1];
        *(bf16x8*)(dst + t * 16) = ra0;
        *(bf16x8*)(dst + 4096 + t * 16) = ra1;
        *(bf16x8*)(dst + 8192 + t * 16) = rb0;
        int jp = j + 2 < 32 ? j + 2 : 31;
        ra0 = *(const bf16x8*)(ag0 + jp * 32);
        ra1 = *(const bf16x8*)(ag1 + jp * 32);
        rb0 = *(const bf16x8*)(bg0 + jp * 32);

        const bf16* As = (const bf16*)lds[j & 1];
        const bf16* Bs = (const bf16*)(lds[j & 1] + 8192);
        bf16x8 af[4], bfr[2];
#pragma unroll
        for (int mi = 0; mi < 4; mi++) {
            int row = wm + mi * 16 + l16;
            af[mi] = *(const bf16x8*)(&As[row * 32 + (g ^ sw) * 8]);
        }
#pragma unroll
        for (int ni = 0; ni < 2; ni++) {
            int row = wn + ni * 16 + l16;
            bfr[ni] = *(const bf16x8*)(&Bs[row * 32 + (g ^ sw) * 8]);
        }
#pragma unroll
        for (int mi = 0; mi < 4; mi++)
#pragma unroll
            for (int ni = 0; ni < 2; ni++)
                acc[mi][ni] = MFMA(bfr[ni], af[mi], acc[mi][ni]);  // D^T
    }

#pragma unroll
    for (int mi = 0; mi < 4; mi++) {
#pragma unroll
        for (int ni = 0; ni < 2; ni++) {
            int row = bm * 128 + wm + mi * 16 + l16;
            int col0 = bn * 64 + wn + ni * 16 + g * 4;
            float4 bv = *(const float4*)(&bias[col0]);
            float4 ov = {acc[mi][ni][0] + bv.x, acc[mi][ni][1] + bv.y,
                         acc[mi][ni][2] + bv.z, acc[mi][ni][3] + bv.w};
            *(float4*)(&out[(size_t)row * 1024 + col0]) = ov;
        }
    }
}

// ---------------- flash attention (R10: coalesced maskT loads) ----------------
// grid = 512 (32 bh x 16 q-tiles of 128), block = 256 (4 waves x 32 q).
// BK=32, 64 iters. 4 LDS buffers, distance-2 DMA prefetch.
// Mask: maskT[s][q] (pre-scaled by log2e) -> 16 coalesced scalar loads/iter.
// Segment = 18 vmem (16 mask + 2 DMA) -> in-loop s_waitcnt vmcnt(18)
// (drains ALL of the previous segment regardless of intra-segment order).
__global__ __launch_bounds__(256, 2) void attn_kernel(
    const bf16* __restrict__ Q, const bf16* __restrict__ K,
    const bf16* __restrict__ VT, const float* __restrict__ maskT,
    bf16* __restrict__ vals) {
    __shared__ __attribute__((aligned(16))) char lds[4][8192];  // [buf]: K[0,4K) V[4K,8K)

    int blk = blockIdx.x;
    int bh = ((blk & 7) << 2) | ((blk >> 3) & 3);
    int qt = blk >> 5;                      // 0..15
    int t = threadIdx.x;
    int w = t >> 6, lane = t & 63, g = lane >> 4, l16 = lane & 15;
    int qw = qt * 128 + w * 32;             // wave's 32-q base
    int qA = qw + l16, qB = qw + 16 + l16;

    const bf16* Qp = Q + (size_t)bh * 2048 * 64;
    const bf16* Kp = K + (size_t)bh * 2048 * 64;
    const bf16* Vp = VT + (size_t)bh * 64 * 2048;

    int ks_row = t >> 3;
    int ks_cblk = (t & 7) ^ (ks_row & 7);
    const bf16* kg = Kp + ks_row * 64 + ks_cblk * 8;
    int vs_d = t >> 2;
    int vs_sblk = (t & 3) ^ ((t >> 3) & 3);
    const bf16* vg = Vp + (size_t)vs_d * 2048 + vs_sblk * 8;

    const float SCL = 0.125f * 1.44269504089f;

    bf16x8 qa0 = *(const bf16x8*)(&Qp[(size_t)(qw + l16) * 64 + g * 8]);
    bf16x8 qa1 = *(const bf16x8*)(&Qp[(size_t)(qw + l16) * 64 + 32 + g * 8]);
    bf16x8 qb0 = *(const bf16x8*)(&Qp[(size_t)(qw + 16 + l16) * 64 + g * 8]);
    bf16x8 qb1 = *(const bf16x8*)(&Qp[(size_t)(qw + 16 + l16) * 64 + 32 + g * 8]);
    load_lds16(kg + 0, &lds[0][t * 16]);
    load_lds16(vg + 0, &lds[0][4096 + t * 16]);
    float mA[8], mB[8];
#pragma unroll
    for (int ts = 0; ts < 2; ts++)
#pragma unroll
        for (int r = 0; r < 4; r++) {
            size_t srow = (size_t)(ts * 16 + g * 4 + r) * 2048;
            mA[ts * 4 + r] = maskT[srow + qA];
            mB[ts * 4 + r] = maskT[srow + qB];
        }
    load_lds16(kg + 1 * 32 * 64, &lds[1][t * 16]);
    load_lds16(vg + 1 * 32, &lds[1][4096 + t * 16]);
    asm volatile("s_waitcnt vmcnt(0)" ::: "memory");
    asm volatile("s_barrier" ::: "memory");

    f32x4 o[4][2] = {};
    float la = 0.f, lb = 0.f;

    for (int j = 0; j < 64; j++) {
        int buf = j & 3;
        int jm = j + 1 < 64 ? j + 1 : 63;
        float nmA[8], nmB[8];
#pragma unroll
        for (int ts = 0; ts < 2; ts++)
#pragma unroll
            for (int r = 0; r < 4; r++) {
                size_t srow = (size_t)(jm * 32 + ts * 16 + g * 4 + r) * 2048;
                nmA[ts * 4 + r] = maskT[srow + qA];
                nmB[ts * 4 + r] = maskT[srow + qB];
            }
        int jp = j + 2 < 64 ? j + 2 : 63;
        load_lds16(kg + (size_t)jp * 32 * 64, &lds[(j + 2) & 3][t * 16]);
        load_lds16(vg + jp * 32, &lds[(j + 2) & 3][4096 + t * 16]);
        // drain everything but this iteration's own 18 vmem ops
        asm volatile("s_waitcnt vmcnt(18)" ::: "memory");
        asm volatile("s_barrier" ::: "memory");

        float pa[8], pb[8];
#pragma unroll
        for (int ts = 0; ts < 2; ts++) {
            int s0 = ts * 16 + l16;
            int swz = s0 & 7;
            bf16x8 k0 = *(const bf16x8*)(&lds[buf][(s0 * 8 + (g ^ swz)) * 16]);
            bf16x8 k1 = *(const bf16x8*)(&lds[buf][(s0 * 8 + ((4 + g) ^ swz)) * 16]);
            f32x4 sta = {}, stb = {};
            sta = MFMA(k0, qa0, sta);
            sta = MFMA(k1, qa1, sta);
            stb = MFMA(k0, qb0, stb);
            stb = MFMA(k1, qb1, stb);
#pragma unroll
            for (int r = 0; r < 4; r++) {
                pa[ts * 4 + r] = EXP2(sta[r] * SCL + mA[ts * 4 + r]);
                pb[ts * 4 + r] = EXP2(stb[r] * SCL + mB[ts * 4 + r]);
            }
        }
#pragma unroll
        for (int i = 0; i < 8; i++) { la += pa[i]; lb += pb[i]; }

        int selA = (((2 * g) & 3) << 4) | l16;
        int selB = (((2 * g + 1) & 3) << 4) | l16;
        bool hi = (g & 2) != 0;
        union { int i[4]; bf16x8 v; } pua, pub;
        {
            union { bf16x2 h; int i; } u;
            int dw0, dw1, dw2, dw3;
            u.h = bf16x2{(bf16)pa[0], (bf16)pa[1]}; dw0 = u.i;
            u.h = bf16x2{(bf16)pa[2], (bf16)pa[3]}; dw1 = u.i;
            u.h = bf16x2{(bf16)pa[4], (bf16)pa[5]}; dw2 = u.i;
            u.h = bf16x2{(bf16)pa[6], (bf16)pa[7]}; dw3 = u.i;
            int t0a = __shfl(dw0, selA, 64), t2a = __shfl(dw2, selA, 64);
            int t1a = __shfl(dw1, selA, 64), t3a = __shfl(dw3, selA, 64);
            int t0b = __shfl(dw0, selB, 64), t2b = __shfl(dw2, selB, 64);
            int t1b = __shfl(dw1, selB, 64), t3b = __shfl(dw3, selB, 64);
            pua.i[0] = hi ? t2a : t0a;
            pua.i[1] = hi ? t3a : t1a;
            pua.i[2] = hi ? t2b : t0b;
            pua.i[3] = hi ? t3b : t1b;
        }
        {
            union { bf16x2 h; int i; } u;
            int dw0, dw1, dw2, dw3;
            u.h = bf16x2{(bf16)pb[0], (bf16)pb[1]}; dw0 = u.i;
            u.h = bf16x2{(bf16)pb[2], (bf16)pb[3]}; dw1 = u.i;
            u.h = bf16x2{(bf16)pb[4], (bf16)pb[5]}; dw2 = u.i;
            u.h = bf16x2{(bf16)pb[6], (bf16)pb[7]}; dw3 = u.i;
            int t0a = __shfl(dw0, selA, 64), t2a = __shfl(dw2, selA, 64);
            int t1a = __shfl(dw1, selA, 64), t3a = __shfl(dw3, selA, 64);
            int t0b = __shfl(dw0, selB, 64), t2b = __shfl(dw2, selB, 64);
            int t1b = __shfl(dw1, selB, 64), t3b = __shfl(dw3, selB, 64);
            pub.i[0] = hi ? t2a : t0a;
            pub.i[1] = hi ? t3a : t1a;
            pub.i[2] = hi ? t2b : t0b;
            pub.i[3] = hi ? t3b : t1b;
        }

#pragma unroll
        for (int nc = 0; nc < 4; nc++) {
            int d = nc * 16 + l16;
            int slot = d * 4 + (g ^ ((d >> 1) & 3));
            bf16x8 vf = *(const bf16x8*)(&lds[buf][4096 + slot * 16]);
            o[nc][0] = MFMA(vf, pua.v, o[nc][0]);
            o[nc][1] = MFMA(vf, pub.v, o[nc][1]);
        }

#pragma unroll
        for (int i = 0; i < 8; i++) { mA[i] = nmA[i]; mB[i] = nmB[i]; }
    }
    asm volatile("s_waitcnt vmcnt(0)" ::: "memory");

    la += __shfl_xor(la, 16, 64);
    la += __shfl_xor(la, 32, 64);
    lb += __shfl_xor(lb, 16, 64);
    lb += __shfl_xor(lb, 32, 64);
    int b = bh >> 4, h = bh & 15;
    float lia = 1.f / la, lib = 1.f / lb;
    size_t rowA = (size_t)(b * 2048 + qw + l16);
    size_t rowB = rowA + 16;
#pragma unroll
    for (int nc = 0; nc < 4; nc++) {
        bf16x4 pkA = {(bf16)(o[nc][0][0] * lia), (bf16)(o[nc][0][1] * lia),
                      (bf16)(o[nc][0][2] * lia), (bf16)(o[nc][0][3] * lia)};
        *(bf16x4*)(&vals[rowA * 1024 + h * 64 + nc * 16 + g * 4]) = pkA;
        bf16x4 pkB = {(bf16)(o[nc][1][0] * lib), (bf16)(o[nc][1][1] * lib),
                      (bf16)(o[nc][1][2] * lib), (bf16)(o[nc][1][3] * lib)};
        *(bf16x4*)(&vals[rowB * 1024 + h * 64 + nc * 16 + g * 4]) = pkB;
    }
}

// ---------------- launch ----------------
extern "C" void kernel_launch(void* const* d_in, const int* in_sizes, int n_in,
                              void* d_out, int out_size, void* d_ws, size_t ws_size,
                              hipStream_t stream) {
    const float* x     = (const float*)d_in[0];
    const float* mask  = (const float*)d_in[1];
    const float* w_qkv = (const float*)d_in[2];
    const float* b_qkv = (const float*)d_in[3];
    const float* w_out = (const float*)d_in[4];
    const float* b_out = (const float*)d_in[5];
    float* out = (float*)d_out;

    char* ws = (char*)d_ws;
    size_t off = 0;
    bf16* xb    = (bf16*)(ws + off); off += (size_t)4096 * 1024 * 2;
    bf16* wqkvT = (bf16*)(ws + off); off += (size_t)3072 * 1024 * 2;
    bf16* woutT = (bf16*)(ws + off); off += (size_t)1024 * 1024 * 2;
    bf16* Qa    = (bf16*)(ws + off); off += (size_t)32 * 2048 * 64 * 2;
    bf16* Ka    = (bf16*)(ws + off); off += (size_t)32 * 2048 * 64 * 2;
    bf16* VTa   = (bf16*)(ws + off); off += (size_t)32 * 64 * 2048 * 2;
    bf16* vals  = (bf16*)(ws + off); off += (size_t)4096 * 1024 * 2;
    float* maskT = (float*)(ws + off); off += (size_t)2048 * 2048 * 4;

    cast4_kernel<<<4096, 256, 0, stream>>>(x, xb, 4096 * 1024 / 4);
    transpose_cast_kernel<<<dim3(96, 32), dim3(32, 8), 0, stream>>>(w_qkv, wqkvT, 1024, 3072);
    transpose_cast_kernel<<<dim3(32, 32), dim3(32, 8), 0, stream>>>(w_out, woutT, 1024, 1024);
    transpose_scale_kernel<<<dim3(64, 64), dim3(32, 8), 0, stream>>>(mask, maskT);
    gemm_qkv_kernel<<<dim3(32, 24), 256, 0, stream>>>(xb, wqkvT, b_qkv, Qa, Ka, VTa);
    attn_kernel<<<512, 256, 0, stream>>>(Qa, Ka, VTa, maskT, vals);
    gemm_out_kernel<<<dim3(32, 16), 256, 0, stream>>>(vals, woutT, b_out, out);
}